// Round 2
// 721.216 us; speedup vs baseline: 1.1004x; 1.1004x over previous
//
#include <hip/hip_runtime.h>

#define S_    4
#define E_    8
#define NPS   12500
#define AEVD  1008
#define D1    256
#define D2    192
#define D3    160
#define TM    64
#define NT    ((NPS + TM - 1) / TM)    // 196
#define TG    8                        // tiles per supergroup
#define NG    ((NT + TG - 1) / TG)     // 25
#define ALPHA 0.1f
#define RS    1024                     // gathered aev row length (bf16 elems, zero-padded)
#define NROW  (NT * TM)                // 12544 rows per species

// packed-weight geometry: [kb][nb][lane(64)][8] bf16, K padded to kb*32.
#define KB1 32
#define NB1 16
#define KB2 8
#define NB2 12
#define KB3 6
#define NB3 10

typedef __attribute__((ext_vector_type(8))) short short8;
typedef __attribute__((ext_vector_type(4))) float f32x4;

__device__ __forceinline__ ushort f2bf(float f) {
    unsigned u = __float_as_uint(f);
    unsigned r = u + 0x7FFFu + ((u >> 16) & 1u);   // RNE
    return (ushort)(r >> 16);
}
__device__ __forceinline__ float celu_f(float v) {
    return v > 0.0f ? v : ALPHA * (__expf(v * (1.0f / ALPHA)) - 1.0f);
}
// LDS-only barrier: outstanding global loads stay in flight.
__device__ __forceinline__ void sync_lds() {
    asm volatile("s_waitcnt lgkmcnt(0)" ::: "memory");
    __builtin_amdgcn_s_barrier();
}
// async global->LDS DMA, 16B/lane; LDS dest = wave-uniform base + lane*16
#define GLD16(g, lp) __builtin_amdgcn_global_load_lds( \
    (const __attribute__((address_space(1))) void*)(g), \
    (__attribute__((address_space(3))) void*)(lp), 16, 0, 0)

// ---------------- weight pre-pack: fp32 [se][K][N] -> bf16 fragment order ----------------
__device__ __forceinline__ void pack_body(const float* __restrict__ W, ushort* __restrict__ out,
                                          int Ksrc, int kbs, int nbs, int Nsrc, int b)
{
    const int kb = b % kbs;
    const int se = b / kbs;
    const int t  = threadIdx.x;
    const int l  = t & 63, q = t >> 6;
    const float* Wse = W + (size_t)se * Ksrc * Nsrc;
    for (int i = 0; i < 4; ++i) {
        int nb = q + i * 4;
        if (nb >= nbs) break;
        int n = nb * 16 + (l & 15);
        ushort v[8];
        #pragma unroll
        for (int j = 0; j < 8; ++j) {
            int k = kb * 32 + ((l >> 4) << 3) + j;
            float x = (k < Ksrc) ? Wse[(size_t)k * Nsrc + n] : 0.0f;
            v[j] = f2bf(x);
        }
        uint4 u;
        u.x = (unsigned)v[0] | ((unsigned)v[1] << 16);
        u.y = (unsigned)v[2] | ((unsigned)v[3] << 16);
        u.z = (unsigned)v[4] | ((unsigned)v[5] << 16);
        u.w = (unsigned)v[6] | ((unsigned)v[7] << 16);
        *(uint4*)(out + ((((size_t)se * kbs + kb) * nbs + nb) * 64 + l) * 8) = u;
    }
}

#define PACKB (S_ * E_ * (KB1 + KB2 + KB3))          // 1472
#define GATBS (NROW * (RS / 8) / 256)                // 6272 gather blocks per species
#define GATB  (GATBS * S_)                           // 25088

// prep = weight pack + (optional) aev gather/convert. Gather output:
// [s][12544 rows][1024] bf16, zero-padded at k>=1008 and padded atoms.
__global__ void prep(const float* __restrict__ W1, const float* __restrict__ W2,
                     const float* __restrict__ W3,
                     ushort* __restrict__ o1, ushort* __restrict__ o2, ushort* __restrict__ o3,
                     const float* __restrict__ aev, const int* __restrict__ idx,
                     ushort* __restrict__ aevb)
{
    int b = blockIdx.x;
    if (b < S_ * E_ * KB1)                  { pack_body(W1, o1, AEVD, KB1, NB1, D1, b); return; }
    b -= S_ * E_ * KB1;
    if (b < S_ * E_ * KB2)                  { pack_body(W2, o2, D1,   KB2, NB2, D2, b); return; }
    b -= S_ * E_ * KB2;
    if (b < S_ * E_ * KB3)                  { pack_body(W3, o3, D2,   KB3, NB3, D3, b); return; }
    b -= S_ * E_ * KB3;
    // gather: thread handles one 8-elem (16B) output chunk
    const int s    = b / GATBS;
    const int r    = (b % GATBS) * 256 + threadIdx.x;   // chunk id in species
    const int grow = r >> 7;                            // row 0..12543
    const int k0   = (r & 127) << 3;                    // 0,8,...,1016
    uint4 u = {0u, 0u, 0u, 0u};
    if (grow < NPS && k0 < AEVD) {
        const float* src = aev + (size_t)idx[s * NPS + grow] * AEVD + k0;
        float4 a = *(const float4*)(src);
        float4 c = *(const float4*)(src + 4);
        u.x = (unsigned)f2bf(a.x) | ((unsigned)f2bf(a.y) << 16);
        u.y = (unsigned)f2bf(a.z) | ((unsigned)f2bf(a.w) << 16);
        u.z = (unsigned)f2bf(c.x) | ((unsigned)f2bf(c.y) << 16);
        u.w = (unsigned)f2bf(c.z) | ((unsigned)f2bf(c.w) << 16);
    }
    *(uint4*)(aevb + ((size_t)s * NROW + grow) * RS + k0) = u;
}

// ================= shared layers 2-4 body (identical in both kernels) =================
// wave w owns atoms w*16..w*16+15; lane owns row (atom) w*16+lm.
__device__ __forceinline__ float layers234(ushort* hrow, int se, int l, int kq,
                                           const ushort* __restrict__ W2p,
                                           const ushort* __restrict__ W3p,
                                           const float* __restrict__ b2,
                                           const float* __restrict__ b3,
                                           const float* __restrict__ W4)
{
    // ---- Layer 2: H2^T = W2^T (A-op, regs) x H1^T (B-op = own-row b128 reads) ----
    const ushort* w2se = W2p + (size_t)se * (KB2 * NB2 * 512);
    f32x4 acc2[NB2];
    #pragma unroll
    for (int i = 0; i < NB2; ++i) acc2[i] = (f32x4){0.f, 0.f, 0.f, 0.f};

    #pragma unroll
    for (int ch = 0; ch < 2; ++ch) {
        const int mb0 = ch * 6;
        uint4 A0[6], A1[6];
        auto AL2 = [&](int kb, int i) {
            return *(const uint4*)(w2se + ((size_t)(kb * NB2 + (mb0 + i)) * 64 + l) * 8);
        };
        #pragma unroll
        for (int i = 0; i < 6; ++i) A0[i] = AL2(0, i);
        short8 bf0 = *(const short8*)(hrow + 0 * 32 + kq * 8);
        #pragma unroll
        for (int kb = 0; kb < KB2; kb += 2) {
            short8 bf1 = *(const short8*)(hrow + (kb + 1) * 32 + kq * 8);
            #pragma unroll
            for (int i = 0; i < 6; ++i) A1[i] = AL2(kb + 1, i);
            #pragma unroll
            for (int i = 0; i < 6; ++i)
                acc2[mb0 + i] = __builtin_amdgcn_mfma_f32_16x16x32_bf16(*(short8*)&A0[i], bf0, acc2[mb0 + i], 0, 0, 0);
            if (kb + 2 < KB2) {
                bf0 = *(const short8*)(hrow + (kb + 2) * 32 + kq * 8);
                #pragma unroll
                for (int i = 0; i < 6; ++i) A0[i] = AL2(kb + 2, i);
            }
            #pragma unroll
            for (int i = 0; i < 6; ++i)
                acc2[mb0 + i] = __builtin_amdgcn_mfma_f32_16x16x32_bf16(*(short8*)&A1[i], bf1, acc2[mb0 + i], 0, 0, 0);
        }
    }
    // L2 epilogue: lane writes 4 consecutive features of ITS OWN row (b64), H1->H2 in place.
    #pragma unroll
    for (int mb = 0; mb < NB2; ++mb) {
        float4 bv = *(const float4*)&b2[se * D2 + mb * 16 + kq * 4];
        uint2 u;
        u.x = (unsigned)f2bf(celu_f(acc2[mb][0] + bv.x)) | ((unsigned)f2bf(celu_f(acc2[mb][1] + bv.y)) << 16);
        u.y = (unsigned)f2bf(celu_f(acc2[mb][2] + bv.z)) | ((unsigned)f2bf(celu_f(acc2[mb][3] + bv.w)) << 16);
        *(uint2*)(hrow + mb * 16 + kq * 4) = u;
    }

    // ---- Layer 3: H3^T = W3^T x H2^T (same structure, K=192) ----
    const ushort* w3se = W3p + (size_t)se * (KB3 * NB3 * 512);
    f32x4 acc3[NB3];
    #pragma unroll
    for (int i = 0; i < NB3; ++i) acc3[i] = (f32x4){0.f, 0.f, 0.f, 0.f};

    #pragma unroll
    for (int ch = 0; ch < 2; ++ch) {
        const int mb0 = ch * 5;
        uint4 A0[5], A1[5];
        auto AL3 = [&](int kb, int i) {
            return *(const uint4*)(w3se + ((size_t)(kb * NB3 + (mb0 + i)) * 64 + l) * 8);
        };
        #pragma unroll
        for (int i = 0; i < 5; ++i) A0[i] = AL3(0, i);
        short8 bf0 = *(const short8*)(hrow + 0 * 32 + kq * 8);
        #pragma unroll
        for (int kb = 0; kb < KB3; kb += 2) {
            short8 bf1 = *(const short8*)(hrow + (kb + 1) * 32 + kq * 8);
            #pragma unroll
            for (int i = 0; i < 5; ++i) A1[i] = AL3(kb + 1, i);
            #pragma unroll
            for (int i = 0; i < 5; ++i)
                acc3[mb0 + i] = __builtin_amdgcn_mfma_f32_16x16x32_bf16(*(short8*)&A0[i], bf0, acc3[mb0 + i], 0, 0, 0);
            if (kb + 2 < KB3) {
                bf0 = *(const short8*)(hrow + (kb + 2) * 32 + kq * 8);
                #pragma unroll
                for (int i = 0; i < 5; ++i) A0[i] = AL3(kb + 2, i);
            }
            #pragma unroll
            for (int i = 0; i < 5; ++i)
                acc3[mb0 + i] = __builtin_amdgcn_mfma_f32_16x16x32_bf16(*(short8*)&A1[i], bf1, acc3[mb0 + i], 0, 0, 0);
        }
    }

    // ---- Layer 4: fold entirely in registers ----
    float e = 0.0f;
    #pragma unroll
    for (int mb = 0; mb < NB3; ++mb) {
        float4 b3v = *(const float4*)&b3[se * D3 + mb * 16 + kq * 4];
        float4 w4v = *(const float4*)&W4[se * D3 + mb * 16 + kq * 4];
        e += celu_f(acc3[mb][0] + b3v.x) * w4v.x;
        e += celu_f(acc3[mb][1] + b3v.y) * w4v.y;
        e += celu_f(acc3[mb][2] + b3v.z) * w4v.z;
        e += celu_f(acc3[mb][3] + b3v.w) * w4v.w;
    }
    return e;
}

// ---------------- main path: async-DMA A staging from gathered bf16 aev ----------------
__global__ __launch_bounds__(256, 3)
void ani_mfma(const ushort* __restrict__ aevb,
              const ushort* __restrict__ W1p, const ushort* __restrict__ W2p,
              const ushort* __restrict__ W3p,
              const float* __restrict__ b1, const float* __restrict__ b2,
              const float* __restrict__ b3,
              const float* __restrict__ W4, const float* __restrict__ b4,
              float* __restrict__ partials)
{
    const int se   = blockIdx.x & 31;      // XCD = blkid%8 = se%8 -> 4 weight sets/XCD (~2.7MB, L2-resident)
    const int ti   = blockIdx.x >> 5;
    const int tile = blockIdx.y * TG + ti; // 8 tiles x 32 se per group -> aev reused 32x while L2/L3-hot
    if (tile >= NT) return;
    const int s = se >> 3;
    const int t = threadIdx.x;
    const int w = t >> 6, l = t & 63;
    const int lm = l & 15, kq = l >> 4;
    // A-frag read swizzle: logical k-chunk kq of atom row lives at slot kq ^ ((atom>>1)&3)
    const int swz = (kq ^ ((lm >> 1) & 3)) << 3;   // ushort offset within 32-elem row

    __shared__ ushort H1s[TM][D1 + 8];                  // 33792 B; rows reused as per-wave H2 later
    __shared__ __align__(16) ushort Ast[2][TM][32];     // 8192 B; [atom][32 k] bf16, chunk-swizzled

    // per-lane DMA source: wave w stages its 16 atoms (64B/atom/kb); source address
    // pre-applies the inverse swizzle so linear LDS landing = swizzled layout (m173 pattern).
    const int aL  = l >> 2;                          // atom within wave's 16
    const int gch = (l & 3) ^ ((l >> 3) & 3);        // logical chunk fetched into slot l&3
    const ushort* gsrc = aevb + ((size_t)s * NROW + (size_t)tile * TM + w * 16 + aL) * RS + gch * 8;
    ushort* lbase0 = &Ast[0][w * 16][0];
    ushort* lbase1 = &Ast[1][w * 16][0];

    // ================= Layer 1: n-split, async DMA A-staging =================
    const ushort* w1se = W1p + (size_t)se * (KB1 * NB1 * 512);
    const ushort* bptr = w1se + ((size_t)(w * 4) * 64 + l) * 8;

    f32x4 acc1[4][4];
    #pragma unroll
    for (int mi = 0; mi < 4; ++mi)
        #pragma unroll
        for (int j = 0; j < 4; ++j) acc1[mi][j] = (f32x4){0.f, 0.f, 0.f, 0.f};

    uint4 B0[4], B1[4];
    auto loadB = [&](uint4* Bt, int kb) {
        #pragma unroll
        for (int i = 0; i < 4; ++i)
            Bt[i] = *(const uint4*)(bptr + (size_t)kb * (NB1 * 512) + i * 512);
    };
    auto mfma16 = [&](const ushort (*Ab)[32], uint4* Bt) {
        #pragma unroll
        for (int mi = 0; mi < 4; ++mi) {
            short8 af = *(const short8*)&Ab[mi * 16 + lm][swz];
            #pragma unroll
            for (int j = 0; j < 4; ++j)
                acc1[mi][j] = __builtin_amdgcn_mfma_f32_16x16x32_bf16(af, *(short8*)&Bt[j], acc1[mi][j], 0, 0, 0);
        }
    };

    // per kb-phase: {vmcnt(4) [my stage(kb) landed]; barrier; issue stage(kb+1)+loadB(kb+1);
    // MFMA on buf(kb)}. vmcnt never drains to 0 in the loop (T4, counted).
    GLD16(gsrc, lbase0);
    loadB(B0, 0);
    for (int kb = 0; kb < KB1; kb += 2) {
        asm volatile("s_waitcnt vmcnt(4)" ::: "memory");
        __builtin_amdgcn_s_barrier();
        GLD16(gsrc + (kb + 1) * 32, lbase1);
        loadB(B1, kb + 1);
        mfma16(Ast[0], B0);
        asm volatile("s_waitcnt vmcnt(4)" ::: "memory");
        __builtin_amdgcn_s_barrier();
        if (kb + 2 < KB1) {
            GLD16(gsrc + (kb + 2) * 32, lbase0);
            loadB(B0, kb + 2);
        }
        mfma16(Ast[1], B1);
    }
    // L1 epilogue: bias+celu -> H1 (atom-major bf16)
    #pragma unroll
    for (int j = 0; j < 4; ++j) {
        int n = (w * 4 + j) * 16 + lm;
        float bias = b1[se * D1 + n];
        #pragma unroll
        for (int mi = 0; mi < 4; ++mi)
            #pragma unroll
            for (int r = 0; r < 4; ++r)
                H1s[mi * 16 + kq * 4 + r][n] = f2bf(celu_f(acc1[mi][j][r] + bias));
    }
    sync_lds();   // LAST barrier: H1 visible to all waves

    ushort* hrow = &H1s[w * 16 + lm][0];
    float e = layers234(hrow, se, l, kq, W2p, W3p, b2, b3, W4);

    if (tile * TM + w * 16 + lm >= NPS) e = 0.0f;   // mask padded atoms (gathered as zero rows)
    #pragma unroll
    for (int o = 32; o > 0; o >>= 1) e += __shfl_xor(e, o);

    float* red = (float*)&Ast[0][0][0];             // Ast dead (all waves past L1 via barrier)
    if (l == 0) red[w] = e;
    __syncthreads();
    if (t == 0) {
        int nv = NPS - tile * TM; if (nv > TM) nv = TM;
        partials[tile * (S_ * E_) + se] = red[0] + red[1] + red[2] + red[3] + (float)nv * b4[se];
    }
}

// ---------------- fallback path: proven register-staging kernel (fp32 aev + idx) ----------------
__global__ __launch_bounds__(256, 3)
void ani_mfma_fb(const float* __restrict__ aev, const int* __restrict__ idx,
                 const ushort* __restrict__ W1p, const ushort* __restrict__ W2p,
                 const ushort* __restrict__ W3p,
                 const float* __restrict__ b1, const float* __restrict__ b2,
                 const float* __restrict__ b3,
                 const float* __restrict__ W4, const float* __restrict__ b4,
                 float* __restrict__ partials)
{
    const int se   = blockIdx.x & 31;
    const int ti   = blockIdx.x >> 5;
    const int tile = blockIdx.y * TG + ti;
    if (tile >= NT) return;
    const int s = se >> 3;
    const int t = threadIdx.x;
    const int w = t >> 6, l = t & 63;
    const int lm = l & 15, kq = l >> 4;

    __shared__ ushort H1s[TM][D1 + 8];
    __shared__ __align__(16) ushort Ast[2][4][TM][8];

    const int srow = tile * TM + l;
    const int src  = srow < NPS ? srow : NPS - 1;
    const float* arowp = aev + (size_t)idx[s * NPS + src] * AEVD;
    const int wo = w * 8;

    const ushort* w1se = W1p + (size_t)se * (KB1 * NB1 * 512);

    f32x4 acc1[4][4];
    #pragma unroll
    for (int mi = 0; mi < 4; ++mi)
        #pragma unroll
        for (int j = 0; j < 4; ++j) acc1[mi][j] = (f32x4){0.f, 0.f, 0.f, 0.f};

    uint4 B0[4], B1[4];
    float4 na, nbv;

    auto loadB = [&](uint4* Bt, int kb) {
        #pragma unroll
        for (int i = 0; i < 4; ++i)
            Bt[i] = *(const uint4*)(w1se + ((size_t)(kb * NB1 + (w * 4 + i)) * 64 + l) * 8);
    };
    auto stageA = [&](int kbw) {
        short8 v;
        v[0] = (short)f2bf(na.x);  v[1] = (short)f2bf(na.y);
        v[2] = (short)f2bf(na.z);  v[3] = (short)f2bf(na.w);
        v[4] = (short)f2bf(nbv.x); v[5] = (short)f2bf(nbv.y);
        v[6] = (short)f2bf(nbv.z); v[7] = (short)f2bf(nbv.w);
        *(short8*)&Ast[kbw & 1][w][l][0] = v;
        if (kbw + 1 < KB1) {
            int ko = (kbw + 1) * 32 + wo;
            if (ko > AEVD - 8) ko = AEVD - 8;
            na  = *(const float4*)(arowp + ko);
            nbv = *(const float4*)(arowp + ko + 4);
        }
    };
    auto mfma16 = [&](int buf, uint4* Bt) {
        #pragma unroll
        for (int mi = 0; mi < 4; ++mi) {
            short8 af = *(const short8*)&Ast[buf][kq][mi * 16 + lm][0];
            #pragma unroll
            for (int j = 0; j < 4; ++j)
                acc1[mi][j] = __builtin_amdgcn_mfma_f32_16x16x32_bf16(af, *(short8*)&Bt[j], acc1[mi][j], 0, 0, 0);
        }
    };

    {
        float4 ca = *(const float4*)(arowp + wo);
        float4 cb = *(const float4*)(arowp + wo + 4);
        short8 v;
        v[0] = (short)f2bf(ca.x); v[1] = (short)f2bf(ca.y);
        v[2] = (short)f2bf(ca.z); v[3] = (short)f2bf(ca.w);
        v[4] = (short)f2bf(cb.x); v[5] = (short)f2bf(cb.y);
        v[6] = (short)f2bf(cb.z); v[7] = (short)f2bf(cb.w);
        *(short8*)&Ast[0][w][l][0] = v;
        na  = *(const float4*)(arowp + 32 + wo);
        nbv = *(const float4*)(arowp + 32 + wo + 4);
        loadB(B0, 0);
        loadB(B1, 1);
        sync_lds();
    }

    for (int kb = 0; kb < KB1; kb += 2) {
        if (kb + 1 < KB1) stageA(kb + 1);
        mfma16(0, B0);
        if (kb + 2 < KB1) loadB(B0, kb + 2);
        sync_lds();
        if (kb + 2 < KB1) stageA(kb + 2);
        mfma16(1, B1);
        if (kb + 3 < KB1) loadB(B1, kb + 3);
        sync_lds();
    }
    #pragma unroll
    for (int j = 0; j < 4; ++j) {
        int n = (w * 4 + j) * 16 + lm;
        float bias = b1[se * D1 + n];
        #pragma unroll
        for (int mi = 0; mi < 4; ++mi)
            #pragma unroll
            for (int r = 0; r < 4; ++r)
                H1s[mi * 16 + kq * 4 + r][n] = f2bf(celu_f(acc1[mi][j][r] + bias));
    }
    sync_lds();

    ushort* hrow = &H1s[w * 16 + lm][0];
    float e = layers234(hrow, se, l, kq, W2p, W3p, b2, b3, W4);

    if (tile * TM + w * 16 + lm >= NPS) e = 0.0f;
    #pragma unroll
    for (int o = 32; o > 0; o >>= 1) e += __shfl_xor(e, o);

    float* red = (float*)&Ast[0][0][0][0];
    if (l == 0) red[w] = e;
    __syncthreads();
    if (t == 0) {
        int nv = NPS - tile * TM; if (nv > TM) nv = TM;
        partials[tile * (S_ * E_) + se] = red[0] + red[1] + red[2] + red[3] + (float)nv * b4[se];
    }
}

__global__ void reduce_partials(const float* __restrict__ p, int n, float* __restrict__ out)
{
    float s = 0.0f;
    for (int i = threadIdx.x; i < n; i += 256) s += p[i];
    #pragma unroll
    for (int o = 32; o > 0; o >>= 1) s += __shfl_xor(s, o);
    __shared__ float sm[4];
    if ((threadIdx.x & 63) == 0) sm[threadIdx.x >> 6] = s;
    __syncthreads();
    if (threadIdx.x == 0) out[0] = (sm[0] + sm[1] + sm[2] + sm[3]) * (1.0f / E_);
}

extern "C" void kernel_launch(void* const* d_in, const int* in_sizes, int n_in,
                              void* d_out, int out_size, void* d_ws, size_t ws_size,
                              hipStream_t stream)
{
    const float* aev = (const float*)d_in[0];
    const int*   idx = (const int*)  d_in[2];
    const float* W1  = (const float*)d_in[3];
    const float* b1  = (const float*)d_in[4];
    const float* W2  = (const float*)d_in[5];
    const float* b2  = (const float*)d_in[6];
    const float* W3  = (const float*)d_in[7];
    const float* b3  = (const float*)d_in[8];
    const float* W4  = (const float*)d_in[9];
    const float* b4  = (const float*)d_in[10];
    float* out = (float*)d_out;

    ushort* w1p = (ushort*)d_ws;
    ushort* w2p = w1p + (size_t)S_ * E_ * KB1 * NB1 * 512;
    ushort* w3p = w2p + (size_t)S_ * E_ * KB2 * NB2 * 512;
    float* partials = (float*)(w3p + (size_t)S_ * E_ * KB3 * NB3 * 512);
    ushort* aevb = (ushort*)(partials + NT * S_ * E_);   // 102.8 MB gathered bf16 aev

    const size_t aevb_bytes = (size_t)S_ * NROW * RS * sizeof(ushort);
    const size_t need = ((char*)aevb - (char*)d_ws) + aevb_bytes;

    dim3 grid(32 * TG, NG);   // supertile: 8 tiles x 32 se per group; XCD=se%8

    if (ws_size >= need) {
        // main path: gather+convert aev once, then async-DMA staging
        prep<<<PACKB + GATB, 256, 0, stream>>>(W1, W2, W3, w1p, w2p, w3p, aev, idx, aevb);
        ani_mfma<<<grid, 256, 0, stream>>>(aevb, w1p, w2p, w3p,
                                           b1, b2, b3, W4, b4, partials);
    } else {
        // fallback: workspace too small for the gathered image — proven register-staging path
        prep<<<PACKB, 256, 0, stream>>>(W1, W2, W3, w1p, w2p, w3p, aev, idx, (ushort*)partials);
        ani_mfma_fb<<<grid, 256, 0, stream>>>(aev, idx, w1p, w2p, w3p,
                                              b1, b2, b3, W4, b4, partials);
    }
    reduce_partials<<<1, 256, 0, stream>>>(partials, NT * S_ * E_, out);
}

// Round 3
// 666.758 us; speedup vs baseline: 1.1903x; 1.0817x over previous
//
#include <hip/hip_runtime.h>

#define S_    4
#define E_    8
#define NPS   12500
#define AEVD  1008
#define D1    256
#define D2    192
#define D3    160
#define TM    64
#define NT    ((NPS + TM - 1) / TM)    // 196
#define TG    8                        // tiles per supergroup
#define NG    ((NT + TG - 1) / TG)     // 25
#define ALPHA 0.1f
#define RS    1024                     // gathered aev row length (bf16 elems, zero-padded)
#define NROW  (NT * TM)                // 12544 rows per species

// packed-weight geometry: [kb][nb][lane(64)][8] bf16, K padded to kb*32.
#define KB1 32
#define NB1 16
#define KB2 8
#define NB2 12
#define KB3 6
#define NB3 10

typedef __attribute__((ext_vector_type(8))) short short8;
typedef __attribute__((ext_vector_type(4))) float f32x4;

__device__ __forceinline__ ushort f2bf(float f) {
    unsigned u = __float_as_uint(f);
    unsigned r = u + 0x7FFFu + ((u >> 16) & 1u);   // RNE
    return (ushort)(r >> 16);
}
__device__ __forceinline__ float celu_f(float v) {
    return v > 0.0f ? v : ALPHA * (__expf(v * (1.0f / ALPHA)) - 1.0f);
}
// LDS-only barrier: outstanding global loads stay in flight.
__device__ __forceinline__ void sync_lds() {
    asm volatile("s_waitcnt lgkmcnt(0)" ::: "memory");
    __builtin_amdgcn_s_barrier();
}
// async global->LDS DMA, 16B/lane; LDS dest = wave-uniform base + lane*16
#define GLD16(g, lp) __builtin_amdgcn_global_load_lds( \
    (const __attribute__((address_space(1))) void*)(g), \
    (__attribute__((address_space(3))) void*)(lp), 16, 0, 0)

// ---------------- weight pre-pack: fp32 [se][K][N] -> bf16 fragment order ----------------
__device__ __forceinline__ void pack_body(const float* __restrict__ W, ushort* __restrict__ out,
                                          int Ksrc, int kbs, int nbs, int Nsrc, int b)
{
    const int kb = b % kbs;
    const int se = b / kbs;
    const int t  = threadIdx.x;
    const int l  = t & 63, q = t >> 6;
    const float* Wse = W + (size_t)se * Ksrc * Nsrc;
    for (int i = 0; i < 4; ++i) {
        int nb = q + i * 4;
        if (nb >= nbs) break;
        int n = nb * 16 + (l & 15);
        ushort v[8];
        #pragma unroll
        for (int j = 0; j < 8; ++j) {
            int k = kb * 32 + ((l >> 4) << 3) + j;
            float x = (k < Ksrc) ? Wse[(size_t)k * Nsrc + n] : 0.0f;
            v[j] = f2bf(x);
        }
        uint4 u;
        u.x = (unsigned)v[0] | ((unsigned)v[1] << 16);
        u.y = (unsigned)v[2] | ((unsigned)v[3] << 16);
        u.z = (unsigned)v[4] | ((unsigned)v[5] << 16);
        u.w = (unsigned)v[6] | ((unsigned)v[7] << 16);
        *(uint4*)(out + ((((size_t)se * kbs + kb) * nbs + nb) * 64 + l) * 8) = u;
    }
}

#define PACKB (S_ * E_ * (KB1 + KB2 + KB3))          // 1472
#define GATBS (NROW * (RS / 8) / 256)                // 6272 gather blocks per species
#define GATB  (GATBS * S_)                           // 25088

// prep = weight pack + aev gather/convert. Gather output: [s][12544 rows][1024] bf16,
// zero-padded at k>=1008 and padded atoms.
__global__ void prep(const float* __restrict__ W1, const float* __restrict__ W2,
                     const float* __restrict__ W3,
                     ushort* __restrict__ o1, ushort* __restrict__ o2, ushort* __restrict__ o3,
                     const float* __restrict__ aev, const int* __restrict__ idx,
                     ushort* __restrict__ aevb)
{
    int b = blockIdx.x;
    if (b < S_ * E_ * KB1)                  { pack_body(W1, o1, AEVD, KB1, NB1, D1, b); return; }
    b -= S_ * E_ * KB1;
    if (b < S_ * E_ * KB2)                  { pack_body(W2, o2, D1,   KB2, NB2, D2, b); return; }
    b -= S_ * E_ * KB2;
    if (b < S_ * E_ * KB3)                  { pack_body(W3, o3, D2,   KB3, NB3, D3, b); return; }
    b -= S_ * E_ * KB3;
    const int s    = b / GATBS;
    const int r    = (b % GATBS) * 256 + threadIdx.x;   // chunk id in species
    const int grow = r >> 7;                            // row 0..12543
    const int k0   = (r & 127) << 3;                    // 0,8,...,1016
    uint4 u = {0u, 0u, 0u, 0u};
    if (grow < NPS && k0 < AEVD) {
        const float* src = aev + (size_t)idx[s * NPS + grow] * AEVD + k0;
        float4 a = *(const float4*)(src);
        float4 c = *(const float4*)(src + 4);
        u.x = (unsigned)f2bf(a.x) | ((unsigned)f2bf(a.y) << 16);
        u.y = (unsigned)f2bf(a.z) | ((unsigned)f2bf(a.w) << 16);
        u.z = (unsigned)f2bf(c.x) | ((unsigned)f2bf(c.y) << 16);
        u.w = (unsigned)f2bf(c.z) | ((unsigned)f2bf(c.w) << 16);
    }
    *(uint4*)(aevb + ((size_t)s * NROW + grow) * RS + k0) = u;
}

// ---------------- fused 4-layer MFMA kernel ----------------
// L1: n-split, async global_load_lds A-staging (counted vmcnt).
// L2/L3: n-split too (NEW): each wave owns 3 feature-blocks for ALL 64 atoms; weights
// load once per block (no 4x redundancy). H in LDS with XOR swizzle (T2):
// phys_col = logical_col ^ ((row&7)<<3). H2 aliases H1 (barrier-separated).
// L4: per-wave masked partials + 16-lane butterfly + LDS cross-wave reduce.
__global__ __launch_bounds__(256, 3)
void ani_mfma(const ushort* __restrict__ aevb,
              const ushort* __restrict__ W1p, const ushort* __restrict__ W2p,
              const ushort* __restrict__ W3p,
              const float* __restrict__ b1, const float* __restrict__ b2,
              const float* __restrict__ b3,
              const float* __restrict__ W4, const float* __restrict__ b4,
              float* __restrict__ partials)
{
    const int se   = blockIdx.x & 31;      // XCD = blkid%8 = se%8 -> 4 weight sets/XCD, L2-resident
    const int ti   = blockIdx.x >> 5;
    const int tile = blockIdx.y * TG + ti;
    if (tile >= NT) return;
    const int s = se >> 3;
    const int t = threadIdx.x;
    const int w = t >> 6, l = t & 63;
    const int lm = l & 15, kq = l >> 4;
    // Ast read swizzle (source-side pre-swizzled, as before)
    const int swz = (kq ^ ((lm >> 1) & 3)) << 3;

    __shared__ ushort H1s[TM * D1];                     // 32768 B, XOR-swizzled cols
    __shared__ __align__(16) ushort Ast[2][TM][32];     // 8192 B; reused as float red[] at end

    const int aL  = l >> 2;
    const int gch = (l & 3) ^ ((l >> 3) & 3);
    const ushort* gsrc = aevb + ((size_t)s * NROW + (size_t)tile * TM + w * 16 + aL) * RS + gch * 8;
    ushort* lbase0 = &Ast[0][w * 16][0];
    ushort* lbase1 = &Ast[1][w * 16][0];

    // ================= Layer 1: n-split, async DMA A-staging =================
    const ushort* w1se = W1p + (size_t)se * (KB1 * NB1 * 512);
    const ushort* bptr = w1se + ((size_t)(w * 4) * 64 + l) * 8;

    f32x4 acc1[4][4];
    #pragma unroll
    for (int mi = 0; mi < 4; ++mi)
        #pragma unroll
        for (int j = 0; j < 4; ++j) acc1[mi][j] = (f32x4){0.f, 0.f, 0.f, 0.f};

    uint4 B0[4], B1[4];
    auto loadB = [&](uint4* Bt, int kb) {
        #pragma unroll
        for (int i = 0; i < 4; ++i)
            Bt[i] = *(const uint4*)(bptr + (size_t)kb * (NB1 * 512) + i * 512);
    };
    auto mfma16 = [&](const ushort (*Ab)[32], uint4* Bt) {
        #pragma unroll
        for (int mi = 0; mi < 4; ++mi) {
            short8 af = *(const short8*)&Ab[mi * 16 + lm][swz];
            #pragma unroll
            for (int j = 0; j < 4; ++j)
                acc1[mi][j] = __builtin_amdgcn_mfma_f32_16x16x32_bf16(af, *(short8*)&Bt[j], acc1[mi][j], 0, 0, 0);
        }
    };

    GLD16(gsrc, lbase0);
    loadB(B0, 0);
    for (int kb = 0; kb < KB1; kb += 2) {
        asm volatile("s_waitcnt vmcnt(4)" ::: "memory");
        __builtin_amdgcn_s_barrier();
        GLD16(gsrc + (kb + 1) * 32, lbase1);
        loadB(B1, kb + 1);
        mfma16(Ast[0], B0);
        asm volatile("s_waitcnt vmcnt(4)" ::: "memory");
        __builtin_amdgcn_s_barrier();
        if (kb + 2 < KB1) {
            GLD16(gsrc + (kb + 2) * 32, lbase0);
            loadB(B0, kb + 2);
        }
        mfma16(Ast[1], B1);
    }
    // L1 epilogue: bias+celu -> H1 (atom-major bf16, swizzled cols)
    #pragma unroll
    for (int j = 0; j < 4; ++j) {
        int n = (w * 4 + j) * 16 + lm;
        float bias = b1[se * D1 + n];
        #pragma unroll
        for (int mi = 0; mi < 4; ++mi)
            #pragma unroll
            for (int r = 0; r < 4; ++r) {
                int row = mi * 16 + kq * 4 + r;
                H1s[row * D1 + (n ^ ((4 * (kq & 1) + r) << 3))] = f2bf(celu_f(acc1[mi][j][r] + bias));
            }
    }
    sync_lds();   // H1 visible to all waves

    // ================= Layer 2: n-split, weights loaded once per block =================
    const int hxA = (lm & 7) << 3;          // (row&7)<<3 for rows mi*16+lm
    const int nbase = w * 3;                // this wave's feature-block start (L2: exact; L3: clamped)
    const ushort* w2se = W2p + (size_t)se * (KB2 * NB2 * 512);

    f32x4 acc2[4][3];
    #pragma unroll
    for (int mi = 0; mi < 4; ++mi)
        #pragma unroll
        for (int i = 0; i < 3; ++i) acc2[mi][i] = (f32x4){0.f, 0.f, 0.f, 0.f};

    {
        uint4 Wb0[3], Wb1[3];
        short8 Ah0[4], Ah1[4];
        auto LW2 = [&](uint4* d, int kb) {
            #pragma unroll
            for (int i = 0; i < 3; ++i)
                d[i] = *(const uint4*)(w2se + ((size_t)(kb * NB2 + nbase + i) * 64 + l) * 8);
        };
        auto LA1 = [&](short8* d, int kb) {
            #pragma unroll
            for (int mi = 0; mi < 4; ++mi)
                d[mi] = *(const short8*)&H1s[(mi * 16 + lm) * D1 + ((kb * 32 + kq * 8) ^ hxA)];
        };
        LW2(Wb0, 0); LA1(Ah0, 0);
        #pragma unroll
        for (int kb = 0; kb < KB2; kb += 2) {
            LW2(Wb1, kb + 1); LA1(Ah1, kb + 1);
            #pragma unroll
            for (int mi = 0; mi < 4; ++mi)
                #pragma unroll
                for (int i = 0; i < 3; ++i)
                    acc2[mi][i] = __builtin_amdgcn_mfma_f32_16x16x32_bf16(Ah0[mi], *(short8*)&Wb0[i], acc2[mi][i], 0, 0, 0);
            if (kb + 2 < KB2) { LW2(Wb0, kb + 2); LA1(Ah0, kb + 2); }
            #pragma unroll
            for (int mi = 0; mi < 4; ++mi)
                #pragma unroll
                for (int i = 0; i < 3; ++i)
                    acc2[mi][i] = __builtin_amdgcn_mfma_f32_16x16x32_bf16(Ah1[mi], *(short8*)&Wb1[i], acc2[mi][i], 0, 0, 0);
        }
    }
    __syncthreads();                        // all H1 reads complete -> safe to overwrite (alias)

    // L2 epilogue: H2 = celu(acc2+b2), bf16, aliased over H1s[0..24K), swizzled cols
    ushort* H2 = H1s;                       // [64][192], row stride D2
    #pragma unroll
    for (int i = 0; i < 3; ++i) {
        int n2 = (nbase + i) * 16 + lm;
        float bias = b2[se * D2 + n2];
        #pragma unroll
        for (int mi = 0; mi < 4; ++mi)
            #pragma unroll
            for (int r = 0; r < 4; ++r) {
                int row = mi * 16 + kq * 4 + r;
                H2[row * D2 + (n2 ^ ((4 * (kq & 1) + r) << 3))] = f2bf(celu_f(acc2[mi][i][r] + bias));
            }
    }
    __syncthreads();                        // H2 complete

    // ================= Layer 3: n-split (10 nb over 4 waves; dup-clamped, masked in L4) ====
    const ushort* w3se = W3p + (size_t)se * (KB3 * NB3 * 512);

    f32x4 acc3[4][3];
    #pragma unroll
    for (int mi = 0; mi < 4; ++mi)
        #pragma unroll
        for (int i = 0; i < 3; ++i) acc3[mi][i] = (f32x4){0.f, 0.f, 0.f, 0.f};

    {
        uint4 Wc0[3], Wc1[3];
        short8 Bh0[4], Bh1[4];
        auto LW3 = [&](uint4* d, int kb) {
            #pragma unroll
            for (int i = 0; i < 3; ++i) {
                int nb = nbase + i; nb = nb < NB3 ? nb : NB3 - 1;   // clamp duplicates
                d[i] = *(const uint4*)(w3se + ((size_t)(kb * NB3 + nb) * 64 + l) * 8);
            }
        };
        auto LA2 = [&](short8* d, int kb) {
            #pragma unroll
            for (int mi = 0; mi < 4; ++mi)
                d[mi] = *(const short8*)&H2[(mi * 16 + lm) * D2 + ((kb * 32 + kq * 8) ^ hxA)];
        };
        LW3(Wc0, 0); LA2(Bh0, 0);
        #pragma unroll
        for (int kb = 0; kb < KB3; kb += 2) {
            LW3(Wc1, kb + 1); LA2(Bh1, kb + 1);
            #pragma unroll
            for (int mi = 0; mi < 4; ++mi)
                #pragma unroll
                for (int i = 0; i < 3; ++i)
                    acc3[mi][i] = __builtin_amdgcn_mfma_f32_16x16x32_bf16(Bh0[mi], *(short8*)&Wc0[i], acc3[mi][i], 0, 0, 0);
            if (kb + 2 < KB3) { LW3(Wc0, kb + 2); LA2(Bh0, kb + 2); }
            #pragma unroll
            for (int mi = 0; mi < 4; ++mi)
                #pragma unroll
                for (int i = 0; i < 3; ++i)
                    acc3[mi][i] = __builtin_amdgcn_mfma_f32_16x16x32_bf16(Bh1[mi], *(short8*)&Wc1[i], acc3[mi][i], 0, 0, 0);
        }
    }

    // ================= Layer 4: masked partials + butterfly + cross-wave reduce ==========
    f32x4 s0 = {0,0,0,0}, s1 = {0,0,0,0}, s2 = {0,0,0,0}, s3 = {0,0,0,0};
    #pragma unroll
    for (int i = 0; i < 3; ++i) {
        bool valid = (nbase + i) < NB3;                  // mask dup-clamped blocks
        int n3 = (valid ? (nbase + i) : 0) * 16 + lm;
        float bv = valid ? b3[se * D3 + n3] : 0.f;
        float wv = valid ? W4[se * D3 + n3] : 0.f;
        #pragma unroll
        for (int r = 0; r < 4; ++r) {
            s0[r] += celu_f(acc3[0][i][r] + bv) * wv;
            s1[r] += celu_f(acc3[1][i][r] + bv) * wv;
            s2[r] += celu_f(acc3[2][i][r] + bv) * wv;
            s3[r] += celu_f(acc3[3][i][r] + bv) * wv;
        }
    }
    // butterfly over the 16-lane (lm) group: every lane ends with all 16 group sums
    #pragma unroll
    for (int o = 1; o <= 8; o <<= 1) {
        #pragma unroll
        for (int r = 0; r < 4; ++r) {
            s0[r] += __shfl_xor(s0[r], o);
            s1[r] += __shfl_xor(s1[r], o);
            s2[r] += __shfl_xor(s2[r], o);
            s3[r] += __shfl_xor(s3[r], o);
        }
    }
    // lane lm supplies row (mi=lm>>2, rr=lm&3) — static select tree, runtime only in address
    f32x4 sm = (lm & 8) ? ((lm & 4) ? s3 : s2) : ((lm & 4) ? s1 : s0);
    float v = (lm & 2) ? ((lm & 1) ? sm[3] : sm[2]) : ((lm & 1) ? sm[1] : sm[0]);

    float* red = (float*)&Ast[0][0][0];     // Ast dead after L1
    red[w * 64 + (lm >> 2) * 16 + kq * 4 + (lm & 3)] = v;
    __syncthreads();
    if (t < 64) {
        int a = t;
        float e = red[a] + red[64 + a] + red[128 + a] + red[192 + a];
        if (tile * TM + a >= NPS) e = 0.0f;
        #pragma unroll
        for (int o = 32; o > 0; o >>= 1) e += __shfl_xor(e, o);
        if (t == 0) {
            int nv = NPS - tile * TM; if (nv > TM) nv = TM;
            partials[tile * (S_ * E_) + se] = e + (float)nv * b4[se];
        }
    }
}

__global__ void reduce_partials(const float* __restrict__ p, int n, float* __restrict__ out)
{
    float s = 0.0f;
    for (int i = threadIdx.x; i < n; i += 256) s += p[i];
    #pragma unroll
    for (int o = 32; o > 0; o >>= 1) s += __shfl_xor(s, o);
    __shared__ float sm[4];
    if ((threadIdx.x & 63) == 0) sm[threadIdx.x >> 6] = s;
    __syncthreads();
    if (threadIdx.x == 0) out[0] = (sm[0] + sm[1] + sm[2] + sm[3]) * (1.0f / E_);
}

extern "C" void kernel_launch(void* const* d_in, const int* in_sizes, int n_in,
                              void* d_out, int out_size, void* d_ws, size_t ws_size,
                              hipStream_t stream)
{
    const float* aev = (const float*)d_in[0];
    const int*   idx = (const int*)  d_in[2];
    const float* W1  = (const float*)d_in[3];
    const float* b1  = (const float*)d_in[4];
    const float* W2  = (const float*)d_in[5];
    const float* b2  = (const float*)d_in[6];
    const float* W3  = (const float*)d_in[7];
    const float* b3  = (const float*)d_in[8];
    const float* W4  = (const float*)d_in[9];
    const float* b4  = (const float*)d_in[10];
    float* out = (float*)d_out;

    ushort* w1p = (ushort*)d_ws;
    ushort* w2p = w1p + (size_t)S_ * E_ * KB1 * NB1 * 512;
    ushort* w3p = w2p + (size_t)S_ * E_ * KB2 * NB2 * 512;
    float* partials = (float*)(w3p + (size_t)S_ * E_ * KB3 * NB3 * 512);
    ushort* aevb = (ushort*)(partials + NT * S_ * E_);   // 102.8 MB gathered bf16 aev

    prep<<<PACKB + GATB, 256, 0, stream>>>(W1, W2, W3, w1p, w2p, w3p, aev, idx, aevb);

    dim3 grid(32 * TG, NG);   // supertile: 8 tiles x 32 se per group; XCD=se%8
    ani_mfma<<<grid, 256, 0, stream>>>(aevb, w1p, w2p, w3p,
                                       b1, b2, b3, W4, b4, partials);
    reduce_partials<<<1, 256, 0, stream>>>(partials, NT * S_ * E_, out);
}

// Round 4
// 658.210 us; speedup vs baseline: 1.2058x; 1.0130x over previous
//
#include <hip/hip_runtime.h>

#define S_    4
#define E_    8
#define NPS   12500
#define AEVD  1008
#define D1    256
#define D2    192
#define D3    160
#define TM    64
#define NT    ((NPS + TM - 1) / TM)    // 196
#define TG    8                        // tiles per supergroup
#define NG    ((NT + TG - 1) / TG)     // 25
#define ALPHA 0.1f
#define RS    1024                     // gathered aev row length (bf16 elems, zero-padded)
#define NROW  (NT * TM)                // 12544 rows per species

// packed-weight geometry: [kb][nb][lane(64)][8] bf16, K padded to kb*32.
#define KB1 32
#define NB1 16
#define KB2 8
#define NB2 12
#define KB3 6
#define NB3 10

typedef __attribute__((ext_vector_type(8))) short short8;
typedef __attribute__((ext_vector_type(4))) float f32x4;

__device__ __forceinline__ ushort f2bf(float f) {
    unsigned u = __float_as_uint(f);
    unsigned r = u + 0x7FFFu + ((u >> 16) & 1u);   // RNE
    return (ushort)(r >> 16);
}
__device__ __forceinline__ float celu_f(float v) {
    return v > 0.0f ? v : ALPHA * (__expf(v * (1.0f / ALPHA)) - 1.0f);
}
// LDS-only barrier: outstanding global loads stay in flight.
__device__ __forceinline__ void sync_lds() {
    asm volatile("s_waitcnt lgkmcnt(0)" ::: "memory");
    __builtin_amdgcn_s_barrier();
}
// async global->LDS DMA, 16B/lane; LDS dest = wave-uniform base + lane*16
#define GLD16(g, lp) __builtin_amdgcn_global_load_lds( \
    (const __attribute__((address_space(1))) void*)(g), \
    (__attribute__((address_space(3))) void*)(lp), 16, 0, 0)

// ---------------- weight pre-pack: fp32 [se][K][N] -> bf16 fragment order ----------------
__device__ __forceinline__ void pack_body(const float* __restrict__ W, ushort* __restrict__ out,
                                          int Ksrc, int kbs, int nbs, int Nsrc, int b)
{
    const int kb = b % kbs;
    const int se = b / kbs;
    const int t  = threadIdx.x;
    const int l  = t & 63, q = t >> 6;
    const float* Wse = W + (size_t)se * Ksrc * Nsrc;
    for (int i = 0; i < 4; ++i) {
        int nb = q + i * 4;
        if (nb >= nbs) break;
        int n = nb * 16 + (l & 15);
        ushort v[8];
        #pragma unroll
        for (int j = 0; j < 8; ++j) {
            int k = kb * 32 + ((l >> 4) << 3) + j;
            float x = (k < Ksrc) ? Wse[(size_t)k * Nsrc + n] : 0.0f;
            v[j] = f2bf(x);
        }
        uint4 u;
        u.x = (unsigned)v[0] | ((unsigned)v[1] << 16);
        u.y = (unsigned)v[2] | ((unsigned)v[3] << 16);
        u.z = (unsigned)v[4] | ((unsigned)v[5] << 16);
        u.w = (unsigned)v[6] | ((unsigned)v[7] << 16);
        *(uint4*)(out + ((((size_t)se * kbs + kb) * nbs + nb) * 64 + l) * 8) = u;
    }
}

#define PACKB (S_ * E_ * (KB1 + KB2 + KB3))          // 1472
#define GATBS (NROW * (RS / 8) / 256)                // 6272 gather blocks per species
#define GATB  (GATBS * S_)                           // 25088

// prep = weight pack + aev gather/convert. Gather output: [s][12544 rows][1024] bf16,
// zero-padded at k>=1008 and padded atoms.
__global__ void prep(const float* __restrict__ W1, const float* __restrict__ W2,
                     const float* __restrict__ W3,
                     ushort* __restrict__ o1, ushort* __restrict__ o2, ushort* __restrict__ o3,
                     const float* __restrict__ aev, const int* __restrict__ idx,
                     ushort* __restrict__ aevb)
{
    int b = blockIdx.x;
    if (b < S_ * E_ * KB1)                  { pack_body(W1, o1, AEVD, KB1, NB1, D1, b); return; }
    b -= S_ * E_ * KB1;
    if (b < S_ * E_ * KB2)                  { pack_body(W2, o2, D1,   KB2, NB2, D2, b); return; }
    b -= S_ * E_ * KB2;
    if (b < S_ * E_ * KB3)                  { pack_body(W3, o3, D2,   KB3, NB3, D3, b); return; }
    b -= S_ * E_ * KB3;
    const int s    = b / GATBS;
    const int r    = (b % GATBS) * 256 + threadIdx.x;   // chunk id in species
    const int grow = r >> 7;                            // row 0..12543
    const int k0   = (r & 127) << 3;                    // 0,8,...,1016
    uint4 u = {0u, 0u, 0u, 0u};
    if (grow < NPS && k0 < AEVD) {
        const float* src = aev + (size_t)idx[s * NPS + grow] * AEVD + k0;
        float4 a = *(const float4*)(src);
        float4 c = *(const float4*)(src + 4);
        u.x = (unsigned)f2bf(a.x) | ((unsigned)f2bf(a.y) << 16);
        u.y = (unsigned)f2bf(a.z) | ((unsigned)f2bf(a.w) << 16);
        u.z = (unsigned)f2bf(c.x) | ((unsigned)f2bf(c.y) << 16);
        u.w = (unsigned)f2bf(c.z) | ((unsigned)f2bf(c.w) << 16);
    }
    *(uint4*)(aevb + ((size_t)s * NROW + grow) * RS + k0) = u;
}

// ---------------- fused 4-layer MFMA kernel ----------------
// Block mapping (NEW): XCD = blockIdx.x%8 is SPECIES-PURE — each XCD hosts one species
// (4 ensemble members): r=x&7 -> s=r>>1, e=(r&1)*4+((x>>3)&3). Resident L2 set per XCD =
// 2.7 MB weights (all 25 supergroups) + 1 MB aev/group < 4 MB, so weights stop thrashing.
// L1: n-split, async global_load_lds A-staging (counted vmcnt).
// L2/L3: n-split, weights loaded once per block; H in LDS, XOR-swizzled cols.
// L4: masked partials + butterfly + cross-wave reduce.
__global__ __launch_bounds__(256, 3)
void ani_mfma(const ushort* __restrict__ aevb,
              const ushort* __restrict__ W1p, const ushort* __restrict__ W2p,
              const ushort* __restrict__ W3p,
              const float* __restrict__ b1, const float* __restrict__ b2,
              const float* __restrict__ b3,
              const float* __restrict__ W4, const float* __restrict__ b4,
              float* __restrict__ partials)
{
    const int bx   = blockIdx.x;
    const int r8   = bx & 7;                                   // XCD id (round-robin by linear id)
    const int se   = (r8 >> 1) * 8 + (r8 & 1) * 4 + ((bx >> 3) & 3);  // species-pure XCD
    const int ti   = bx >> 5;
    const int tile = blockIdx.y * TG + ti;
    if (tile >= NT) return;
    const int s = se >> 3;
    const int t = threadIdx.x;
    const int w = t >> 6, l = t & 63;
    const int lm = l & 15, kq = l >> 4;
    // Ast read swizzle (source-side pre-swizzled, as before)
    const int swz = (kq ^ ((lm >> 1) & 3)) << 3;

    __shared__ ushort H1s[TM * D1];                     // 32768 B, XOR-swizzled cols
    __shared__ __align__(16) ushort Ast[2][TM][32];     // 8192 B; reused as float red[] at end

    const int aL  = l >> 2;
    const int gch = (l & 3) ^ ((l >> 3) & 3);
    const ushort* gsrc = aevb + ((size_t)s * NROW + (size_t)tile * TM + w * 16 + aL) * RS + gch * 8;
    ushort* lbase0 = &Ast[0][w * 16][0];
    ushort* lbase1 = &Ast[1][w * 16][0];

    // ================= Layer 1: n-split, async DMA A-staging =================
    const ushort* w1se = W1p + (size_t)se * (KB1 * NB1 * 512);
    const ushort* bptr = w1se + ((size_t)(w * 4) * 64 + l) * 8;

    f32x4 acc1[4][4];
    #pragma unroll
    for (int mi = 0; mi < 4; ++mi)
        #pragma unroll
        for (int j = 0; j < 4; ++j) acc1[mi][j] = (f32x4){0.f, 0.f, 0.f, 0.f};

    uint4 B0[4], B1[4];
    auto loadB = [&](uint4* Bt, int kb) {
        #pragma unroll
        for (int i = 0; i < 4; ++i)
            Bt[i] = *(const uint4*)(bptr + (size_t)kb * (NB1 * 512) + i * 512);
    };
    auto mfma16 = [&](const ushort (*Ab)[32], uint4* Bt) {
        #pragma unroll
        for (int mi = 0; mi < 4; ++mi) {
            short8 af = *(const short8*)&Ab[mi * 16 + lm][swz];
            #pragma unroll
            for (int j = 0; j < 4; ++j)
                acc1[mi][j] = __builtin_amdgcn_mfma_f32_16x16x32_bf16(af, *(short8*)&Bt[j], acc1[mi][j], 0, 0, 0);
        }
    };

    GLD16(gsrc, lbase0);
    loadB(B0, 0);
    for (int kb = 0; kb < KB1; kb += 2) {
        asm volatile("s_waitcnt vmcnt(4)" ::: "memory");
        __builtin_amdgcn_s_barrier();
        GLD16(gsrc + (kb + 1) * 32, lbase1);
        loadB(B1, kb + 1);
        mfma16(Ast[0], B0);
        asm volatile("s_waitcnt vmcnt(4)" ::: "memory");
        __builtin_amdgcn_s_barrier();
        if (kb + 2 < KB1) {
            GLD16(gsrc + (kb + 2) * 32, lbase0);
            loadB(B0, kb + 2);
        }
        mfma16(Ast[1], B1);
    }
    // L1 epilogue: bias+celu -> H1 (atom-major bf16, swizzled cols)
    #pragma unroll
    for (int j = 0; j < 4; ++j) {
        int n = (w * 4 + j) * 16 + lm;
        float bias = b1[se * D1 + n];
        #pragma unroll
        for (int mi = 0; mi < 4; ++mi)
            #pragma unroll
            for (int r = 0; r < 4; ++r) {
                int row = mi * 16 + kq * 4 + r;
                H1s[row * D1 + (n ^ ((4 * (kq & 1) + r) << 3))] = f2bf(celu_f(acc1[mi][j][r] + bias));
            }
    }
    sync_lds();   // H1 visible to all waves

    // ================= Layer 2: n-split, weights loaded once per block =================
    const int hxA = (lm & 7) << 3;          // (row&7)<<3 for rows mi*16+lm
    const int nbase = w * 3;                // this wave's feature-block start (L2: exact; L3: clamped)
    const ushort* w2se = W2p + (size_t)se * (KB2 * NB2 * 512);

    f32x4 acc2[4][3];
    #pragma unroll
    for (int mi = 0; mi < 4; ++mi)
        #pragma unroll
        for (int i = 0; i < 3; ++i) acc2[mi][i] = (f32x4){0.f, 0.f, 0.f, 0.f};

    {
        uint4 Wb0[3], Wb1[3];
        short8 Ah0[4], Ah1[4];
        auto LW2 = [&](uint4* d, int kb) {
            #pragma unroll
            for (int i = 0; i < 3; ++i)
                d[i] = *(const uint4*)(w2se + ((size_t)(kb * NB2 + nbase + i) * 64 + l) * 8);
        };
        auto LA1 = [&](short8* d, int kb) {
            #pragma unroll
            for (int mi = 0; mi < 4; ++mi)
                d[mi] = *(const short8*)&H1s[(mi * 16 + lm) * D1 + ((kb * 32 + kq * 8) ^ hxA)];
        };
        LW2(Wb0, 0); LA1(Ah0, 0);
        #pragma unroll
        for (int kb = 0; kb < KB2; kb += 2) {
            LW2(Wb1, kb + 1); LA1(Ah1, kb + 1);
            #pragma unroll
            for (int mi = 0; mi < 4; ++mi)
                #pragma unroll
                for (int i = 0; i < 3; ++i)
                    acc2[mi][i] = __builtin_amdgcn_mfma_f32_16x16x32_bf16(Ah0[mi], *(short8*)&Wb0[i], acc2[mi][i], 0, 0, 0);
            if (kb + 2 < KB2) { LW2(Wb0, kb + 2); LA1(Ah0, kb + 2); }
            #pragma unroll
            for (int mi = 0; mi < 4; ++mi)
                #pragma unroll
                for (int i = 0; i < 3; ++i)
                    acc2[mi][i] = __builtin_amdgcn_mfma_f32_16x16x32_bf16(Ah1[mi], *(short8*)&Wb1[i], acc2[mi][i], 0, 0, 0);
        }
    }
    __syncthreads();                        // all H1 reads complete -> safe to overwrite (alias)

    // L2 epilogue: H2 = celu(acc2+b2), bf16, aliased over H1s[0..24K), swizzled cols
    ushort* H2 = H1s;                       // [64][192], row stride D2
    #pragma unroll
    for (int i = 0; i < 3; ++i) {
        int n2 = (nbase + i) * 16 + lm;
        float bias = b2[se * D2 + n2];
        #pragma unroll
        for (int mi = 0; mi < 4; ++mi)
            #pragma unroll
            for (int r = 0; r < 4; ++r) {
                int row = mi * 16 + kq * 4 + r;
                H2[row * D2 + (n2 ^ ((4 * (kq & 1) + r) << 3))] = f2bf(celu_f(acc2[mi][i][r] + bias));
            }
    }
    __syncthreads();                        // H2 complete

    // ================= Layer 3: n-split (10 nb over 4 waves; dup-clamped, masked in L4) ====
    const ushort* w3se = W3p + (size_t)se * (KB3 * NB3 * 512);

    f32x4 acc3[4][3];
    #pragma unroll
    for (int mi = 0; mi < 4; ++mi)
        #pragma unroll
        for (int i = 0; i < 3; ++i) acc3[mi][i] = (f32x4){0.f, 0.f, 0.f, 0.f};

    {
        uint4 Wc0[3], Wc1[3];
        short8 Bh0[4], Bh1[4];
        auto LW3 = [&](uint4* d, int kb) {
            #pragma unroll
            for (int i = 0; i < 3; ++i) {
                int nb = nbase + i; nb = nb < NB3 ? nb : NB3 - 1;   // clamp duplicates
                d[i] = *(const uint4*)(w3se + ((size_t)(kb * NB3 + nb) * 64 + l) * 8);
            }
        };
        auto LA2 = [&](short8* d, int kb) {
            #pragma unroll
            for (int mi = 0; mi < 4; ++mi)
                d[mi] = *(const short8*)&H2[(mi * 16 + lm) * D2 + ((kb * 32 + kq * 8) ^ hxA)];
        };
        LW3(Wc0, 0); LA2(Bh0, 0);
        #pragma unroll
        for (int kb = 0; kb < KB3; kb += 2) {
            LW3(Wc1, kb + 1); LA2(Bh1, kb + 1);
            #pragma unroll
            for (int mi = 0; mi < 4; ++mi)
                #pragma unroll
                for (int i = 0; i < 3; ++i)
                    acc3[mi][i] = __builtin_amdgcn_mfma_f32_16x16x32_bf16(Bh0[mi], *(short8*)&Wc0[i], acc3[mi][i], 0, 0, 0);
            if (kb + 2 < KB3) { LW3(Wc0, kb + 2); LA2(Bh0, kb + 2); }
            #pragma unroll
            for (int mi = 0; mi < 4; ++mi)
                #pragma unroll
                for (int i = 0; i < 3; ++i)
                    acc3[mi][i] = __builtin_amdgcn_mfma_f32_16x16x32_bf16(Bh1[mi], *(short8*)&Wc1[i], acc3[mi][i], 0, 0, 0);
        }
    }

    // ================= Layer 4: masked partials + butterfly + cross-wave reduce ==========
    f32x4 s0 = {0,0,0,0}, s1 = {0,0,0,0}, s2 = {0,0,0,0}, s3 = {0,0,0,0};
    #pragma unroll
    for (int i = 0; i < 3; ++i) {
        bool valid = (nbase + i) < NB3;                  // mask dup-clamped blocks
        int n3 = (valid ? (nbase + i) : 0) * 16 + lm;
        float bv = valid ? b3[se * D3 + n3] : 0.f;
        float wv = valid ? W4[se * D3 + n3] : 0.f;
        #pragma unroll
        for (int r = 0; r < 4; ++r) {
            s0[r] += celu_f(acc3[0][i][r] + bv) * wv;
            s1[r] += celu_f(acc3[1][i][r] + bv) * wv;
            s2[r] += celu_f(acc3[2][i][r] + bv) * wv;
            s3[r] += celu_f(acc3[3][i][r] + bv) * wv;
        }
    }
    // butterfly over the 16-lane (lm) group: every lane ends with all 16 group sums
    #pragma unroll
    for (int o = 1; o <= 8; o <<= 1) {
        #pragma unroll
        for (int r = 0; r < 4; ++r) {
            s0[r] += __shfl_xor(s0[r], o);
            s1[r] += __shfl_xor(s1[r], o);
            s2[r] += __shfl_xor(s2[r], o);
            s3[r] += __shfl_xor(s3[r], o);
        }
    }
    // lane lm supplies row (mi=lm>>2, rr=lm&3) — static select tree, runtime only in address
    f32x4 sm = (lm & 8) ? ((lm & 4) ? s3 : s2) : ((lm & 4) ? s1 : s0);
    float v = (lm & 2) ? ((lm & 1) ? sm[3] : sm[2]) : ((lm & 1) ? sm[1] : sm[0]);

    float* red = (float*)&Ast[0][0][0];     // Ast dead after L1
    red[w * 64 + (lm >> 2) * 16 + kq * 4 + (lm & 3)] = v;
    __syncthreads();
    if (t < 64) {
        int a = t;
        float e = red[a] + red[64 + a] + red[128 + a] + red[192 + a];
        if (tile * TM + a >= NPS) e = 0.0f;
        #pragma unroll
        for (int o = 32; o > 0; o >>= 1) e += __shfl_xor(e, o);
        if (t == 0) {
            int nv = NPS - tile * TM; if (nv > TM) nv = TM;
            partials[tile * (S_ * E_) + se] = e + (float)nv * b4[se];
        }
    }
}

__global__ void reduce_partials(const float* __restrict__ p, int n, float* __restrict__ out)
{
    float s = 0.0f;
    for (int i = threadIdx.x; i < n; i += 256) s += p[i];
    #pragma unroll
    for (int o = 32; o > 0; o >>= 1) s += __shfl_xor(s, o);
    __shared__ float sm[4];
    if ((threadIdx.x & 63) == 0) sm[threadIdx.x >> 6] = s;
    __syncthreads();
    if (threadIdx.x == 0) out[0] = (sm[0] + sm[1] + sm[2] + sm[3]) * (1.0f / E_);
}

extern "C" void kernel_launch(void* const* d_in, const int* in_sizes, int n_in,
                              void* d_out, int out_size, void* d_ws, size_t ws_size,
                              hipStream_t stream)
{
    const float* aev = (const float*)d_in[0];
    const int*   idx = (const int*)  d_in[2];
    const float* W1  = (const float*)d_in[3];
    const float* b1  = (const float*)d_in[4];
    const float* W2  = (const float*)d_in[5];
    const float* b2  = (const float*)d_in[6];
    const float* W3  = (const float*)d_in[7];
    const float* b3  = (const float*)d_in[8];
    const float* W4  = (const float*)d_in[9];
    const float* b4  = (const float*)d_in[10];
    float* out = (float*)d_out;

    ushort* w1p = (ushort*)d_ws;
    ushort* w2p = w1p + (size_t)S_ * E_ * KB1 * NB1 * 512;
    ushort* w3p = w2p + (size_t)S_ * E_ * KB2 * NB2 * 512;
    float* partials = (float*)(w3p + (size_t)S_ * E_ * KB3 * NB3 * 512);
    ushort* aevb = (ushort*)(partials + NT * S_ * E_);   // 102.8 MB gathered bf16 aev

    prep<<<PACKB + GATB, 256, 0, stream>>>(W1, W2, W3, w1p, w2p, w3p, aev, idx, aevb);

    dim3 grid(32 * TG, NG);   // supertile: 8 tiles x (4 e x 8 XCD) per group; XCD species-pure
    ani_mfma<<<grid, 256, 0, stream>>>(aevb, w1p, w2p, w3p,
                                       b1, b2, b3, W4, b4, partials);
    reduce_partials<<<1, 256, 0, stream>>>(partials, NT * S_ * E_, out);
}